// Round 1
// baseline (152.892 us; speedup 1.0000x reference)
//
#include <hip/hip_runtime.h>
#include <float.h>

#define SLOPE 0.2f

__device__ __forceinline__ float leaky(float x) { return x > 0.f ? x : SLOPE * x; }

// ---------------------------------------------------------------------------
// Kernel A: per-node MLPs (self + nb) and projections through comb_w1 halves.
//   self_e = mlp2(x, self_*) ; nb_e = mlp2(x, nb_*)
//   s_self = self_e @ comb_w1[:64]  + comb_b1   (bias folded here)
//   s_nb   = nb_e   @ comb_w1[64:]
// 16 nodes per block, 256 threads (4 waves), wave w handles nodes {u*4+w}.
// ---------------------------------------------------------------------------
__global__ __launch_bounds__(256) void node_mlps(
    const float* __restrict__ nodes,
    const float* __restrict__ self_w1, const float* __restrict__ self_b1,
    const float* __restrict__ self_w2, const float* __restrict__ self_b2,
    const float* __restrict__ nb_w1,   const float* __restrict__ nb_b1,
    const float* __restrict__ nb_w2,   const float* __restrict__ nb_b2,
    const float* __restrict__ comb_w1, const float* __restrict__ comb_b1,
    float* __restrict__ self_e, float* __restrict__ nb_e,
    float* __restrict__ s_self, float* __restrict__ s_nb)
{
  __shared__ float x_sh[16][128];
  __shared__ float h_sh[16][64];
  __shared__ float e_sh[16][64];

  const int tid  = threadIdx.x;
  const int lane = tid & 63;
  const int wv   = tid >> 6;
  const int node0 = blockIdx.x * 16;

  // cooperative load: 16 nodes * 128 floats, contiguous in global
  {
    const float4* src = (const float4*)(nodes + (size_t)node0 * 128);
    float4* dst = (float4*)&x_sh[0][0];
    for (int k = tid; k < 16 * 128 / 4; k += 256) dst[k] = src[k];
  }
  __syncthreads();

  for (int p = 0; p < 2; ++p) {
    const float* w1 = p ? nb_w1 : self_w1;
    const float* b1 = p ? nb_b1 : self_b1;
    const float* w2 = p ? nb_w2 : self_w2;
    const float* b2 = p ? nb_b2 : self_b2;

    // layer 1: h = leaky(x @ w1 + b1)
    float acc[4];
    #pragma unroll
    for (int u = 0; u < 4; ++u) acc[u] = b1[lane];
    #pragma unroll 8
    for (int d = 0; d < 128; ++d) {
      float wval = w1[d * 64 + lane];
      #pragma unroll
      for (int u = 0; u < 4; ++u) acc[u] += x_sh[u * 4 + wv][d] * wval;
    }
    #pragma unroll
    for (int u = 0; u < 4; ++u) h_sh[u * 4 + wv][lane] = leaky(acc[u]);
    // wave-local LDS dependency only (each wave reads rows it wrote)

    // layer 2: e = h @ w2 + b2
    #pragma unroll
    for (int u = 0; u < 4; ++u) acc[u] = b2[lane];
    #pragma unroll 8
    for (int c = 0; c < 64; ++c) {
      float wval = w2[c * 64 + lane];
      #pragma unroll
      for (int u = 0; u < 4; ++u) acc[u] += h_sh[u * 4 + wv][c] * wval;
    }
    float* eout = p ? nb_e : self_e;
    #pragma unroll
    for (int u = 0; u < 4; ++u) {
      e_sh[u * 4 + wv][lane] = acc[u];
      eout[(size_t)(node0 + u * 4 + wv) * 64 + lane] = acc[u];
    }

    // projection: s = e @ comb_w1_half (+ comb_b1 for self)
    float sacc[4] = {0.f, 0.f, 0.f, 0.f};
    const float* cw = comb_w1 + (p ? 64 * 64 : 0);
    #pragma unroll 8
    for (int c = 0; c < 64; ++c) {
      float wval = cw[c * 64 + lane];
      #pragma unroll
      for (int u = 0; u < 4; ++u) sacc[u] += e_sh[u * 4 + wv][c] * wval;
    }
    float* sout = p ? s_nb : s_self;
    const float badd = p ? 0.f : comb_b1[lane];
    #pragma unroll
    for (int u = 0; u < 4; ++u)
      sout[(size_t)(node0 + u * 4 + wv) * 64 + lane] = sacc[u] + badd;
  }
}

// ---------------------------------------------------------------------------
// Kernel B: one block per (b,i). Scores over j, masked softmax, aggregation.
// ---------------------------------------------------------------------------
__global__ __launch_bounds__(256) void gat_attn(
    const int* __restrict__ edges,
    const float* __restrict__ comb_w2, const float* __restrict__ comb_b2,
    const float* __restrict__ self_e, const float* __restrict__ nb_e,
    const float* __restrict__ s_self, const float* __restrict__ s_nb,
    float* __restrict__ out)
{
  __shared__ float ss[64];
  __shared__ float w2s[64];
  __shared__ float sc[512];
  __shared__ float red[4];
  __shared__ float part[4][64];

  const int tid  = threadIdx.x;
  const int lane = tid & 63;
  const int wv   = tid >> 6;
  const int node = blockIdx.x;          // b*512 + i
  const int b    = node >> 9;
  const int i    = node & 511;

  if (tid < 64) {
    ss[tid]  = s_self[(size_t)node * 64 + tid];  // comb_b1 already folded in
    w2s[tid] = comb_w2[tid];
  }
  __syncthreads();

  const float cb2 = comb_b2[0];

  // ---- scores (sentinel -FLT_MAX for masked-out) ----
  for (int j = tid; j < 512; j += 256) {
    const bool m = (edges[((size_t)b * 512 + j) * 512 + i] != 0) && (j != i);
    float s = -FLT_MAX;
    if (m) {
      const float4* row = (const float4*)(s_nb + ((size_t)b * 512 + j) * 64);
      float dot = 0.f;
      #pragma unroll
      for (int q = 0; q < 16; ++q) {
        float4 v = row[q];
        dot += leaky(ss[4 * q + 0] + v.x) * w2s[4 * q + 0];
        dot += leaky(ss[4 * q + 1] + v.y) * w2s[4 * q + 1];
        dot += leaky(ss[4 * q + 2] + v.z) * w2s[4 * q + 2];
        dot += leaky(ss[4 * q + 3] + v.w) * w2s[4 * q + 3];
      }
      s = dot + cb2;
    }
    sc[j] = s;
  }
  __syncthreads();

  // ---- max reduction ----
  float v = fmaxf(sc[tid], sc[tid + 256]);
  #pragma unroll
  for (int off = 32; off; off >>= 1) v = fmaxf(v, __shfl_xor(v, off, 64));
  if (lane == 0) red[wv] = v;
  __syncthreads();
  const float mx = fmaxf(fmaxf(red[0], red[1]), fmaxf(red[2], red[3]));
  const bool has_nb = (mx > -0.5f * FLT_MAX);
  if (!has_nb) {                        // block-uniform: whole row masked out
    if (tid < 64) out[(size_t)node * 64 + tid] = 0.f;
    return;
  }

  // ---- exp + sum (each thread owns sc[tid], sc[tid+256]) ----
  float lsum = 0.f;
  for (int j = tid; j < 512; j += 256) {
    const float e = (sc[j] > -0.5f * FLT_MAX) ? __expf(sc[j] - mx) : 0.f;
    sc[j] = e;
    lsum += e;
  }
  #pragma unroll
  for (int off = 32; off; off >>= 1) lsum += __shfl_xor(lsum, off, 64);
  __syncthreads();                      // sc writes visible; mx reads done
  if (lane == 0) red[wv] = lsum;
  __syncthreads();
  const float inv = 1.f / (red[0] + red[1] + red[2] + red[3]);

  // ---- aggregation: wave wv covers j in [wv*128, wv*128+128) ----
  float a = 0.f;
  const float* nbb = nb_e + (size_t)b * 512 * 64;
  for (int j = wv * 128; j < wv * 128 + 128; ++j) {
    const float wj = sc[j];             // wave-uniform -> uniform branch
    if (wj != 0.f) a += wj * nbb[(size_t)j * 64 + lane];
  }
  part[wv][lane] = a;
  __syncthreads();
  if (tid < 64) {
    const float tot =
        (part[0][tid] + part[1][tid] + part[2][tid] + part[3][tid]) * inv +
        self_e[(size_t)node * 64 + tid];
    out[(size_t)node * 64 + tid] = tot;
  }
}

// ---------------------------------------------------------------------------
extern "C" void kernel_launch(void* const* d_in, const int* in_sizes, int n_in,
                              void* d_out, int out_size, void* d_ws, size_t ws_size,
                              hipStream_t stream) {
  const float* nodes   = (const float*)d_in[0];
  const int*   edges   = (const int*)  d_in[1];
  const float* self_w1 = (const float*)d_in[2];
  const float* self_b1 = (const float*)d_in[3];
  const float* self_w2 = (const float*)d_in[4];
  const float* self_b2 = (const float*)d_in[5];
  const float* nb_w1   = (const float*)d_in[6];
  const float* nb_b1   = (const float*)d_in[7];
  const float* nb_w2   = (const float*)d_in[8];
  const float* nb_b2   = (const float*)d_in[9];
  const float* comb_w1 = (const float*)d_in[10];
  const float* comb_b1 = (const float*)d_in[11];
  const float* comb_w2 = (const float*)d_in[12];
  const float* comb_b2 = (const float*)d_in[13];

  float* ws     = (float*)d_ws;
  float* self_e = ws;                 // 4096*64
  float* nb_e   = ws + 262144;        // 4096*64
  float* s_self = ws + 524288;        // 4096*64 (comb_b1 folded)
  float* s_nb   = ws + 786432;        // 4096*64

  node_mlps<<<256, 256, 0, stream>>>(
      nodes, self_w1, self_b1, self_w2, self_b2,
      nb_w1, nb_b1, nb_w2, nb_b2, comb_w1, comb_b1,
      self_e, nb_e, s_self, s_nb);

  gat_attn<<<4096, 256, 0, stream>>>(
      edges, comb_w2, comb_b2, self_e, nb_e, s_self, s_nb, (float*)d_out);
}

// Round 2
// 47.471 us; speedup vs baseline: 3.2207x; 3.2207x over previous
//
#include <hip/hip_runtime.h>
#include <float.h>

#define SLOPE 0.2f
// leaky(t) = max(t, SLOPE*t) = 0.6t + 0.4|t|  (for SLOPE=0.2)

__device__ __forceinline__ float leaky(float x) { return fmaxf(x, SLOPE * x); }

// ---------------------------------------------------------------------------
// Kernel A: per-node MLPs + projections + rank-1 score terms.
//   ss = self_e @ comb_w1[:64] + comb_b1          (b1 folded)
//   sn = nb_e   @ comb_w1[64:]
//   sP = 0.6 * sum_k(w2_k * ss_k) + comb_b2       (per node scalar)
//   sQ = 0.6 * sum_k(w2_k * sn_k)
// 512 blocks x 256 thr; 8 nodes/block; each wave owns 2 nodes.
// ---------------------------------------------------------------------------
__global__ __launch_bounds__(256) void node_mlps(
    const float* __restrict__ nodes,
    const float* __restrict__ self_w1, const float* __restrict__ self_b1,
    const float* __restrict__ self_w2, const float* __restrict__ self_b2,
    const float* __restrict__ nb_w1,   const float* __restrict__ nb_b1,
    const float* __restrict__ nb_w2,   const float* __restrict__ nb_b2,
    const float* __restrict__ comb_w1, const float* __restrict__ comb_b1,
    const float* __restrict__ comb_w2, const float* __restrict__ comb_b2,
    float* __restrict__ self_e, float* __restrict__ nb_e,
    float* __restrict__ ss, float* __restrict__ sn,
    float* __restrict__ sP, float* __restrict__ sQ)
{
  __shared__ float x_sh[8][128];
  __shared__ float h_sh[8][64];
  __shared__ float e_sh[8][64];

  const int tid = threadIdx.x, lane = tid & 63, wv = tid >> 6;
  const int node0 = blockIdx.x * 8;

  ((float4*)&x_sh[0][0])[tid] = ((const float4*)(nodes + (size_t)node0 * 128))[tid];
  __syncthreads();

  const int la = wv * 2, lb = la + 1;
  const float w2lane = comb_w2[lane];
  const float cb2 = comb_b2[0];
  const float cb1 = comb_b1[lane];

  for (int p = 0; p < 2; ++p) {
    const float* w1 = p ? nb_w1 : self_w1;
    const float* b1 = p ? nb_b1 : self_b1;
    const float* w2 = p ? nb_w2 : self_w2;
    const float* b2 = p ? nb_b2 : self_b2;
    const float* cw = comb_w1 + (p ? 64 * 64 : 0);

    // ---- layer 1: h = leaky(x @ w1 + b1), dual accumulator chains ----
    float a0 = 0.f, a1 = 0.f, c0 = 0.f, c1 = 0.f;
    #pragma unroll 4
    for (int q = 0; q < 32; ++q) {
      float4 xa = *(const float4*)&x_sh[la][q * 4];
      float4 xb = *(const float4*)&x_sh[lb][q * 4];
      float w_0 = w1[(q * 4 + 0) * 64 + lane];
      float w_1 = w1[(q * 4 + 1) * 64 + lane];
      float w_2 = w1[(q * 4 + 2) * 64 + lane];
      float w_3 = w1[(q * 4 + 3) * 64 + lane];
      a0 += xa.x * w_0; a1 += xa.y * w_1; a0 += xa.z * w_2; a1 += xa.w * w_3;
      c0 += xb.x * w_0; c1 += xb.y * w_1; c0 += xb.z * w_2; c1 += xb.w * w_3;
    }
    {
      float bv = b1[lane];
      h_sh[la][lane] = leaky(a0 + a1 + bv);
      h_sh[lb][lane] = leaky(c0 + c1 + bv);
    }
    __syncthreads();

    // ---- layer 2: e = h @ w2 + b2 ----
    a0 = a1 = c0 = c1 = 0.f;
    #pragma unroll 4
    for (int q = 0; q < 16; ++q) {
      float4 ha = *(const float4*)&h_sh[la][q * 4];
      float4 hb = *(const float4*)&h_sh[lb][q * 4];
      float w_0 = w2[(q * 4 + 0) * 64 + lane];
      float w_1 = w2[(q * 4 + 1) * 64 + lane];
      float w_2 = w2[(q * 4 + 2) * 64 + lane];
      float w_3 = w2[(q * 4 + 3) * 64 + lane];
      a0 += ha.x * w_0; a1 += ha.y * w_1; a0 += ha.z * w_2; a1 += ha.w * w_3;
      c0 += hb.x * w_0; c1 += hb.y * w_1; c0 += hb.z * w_2; c1 += hb.w * w_3;
    }
    float e_a, e_b;
    {
      float bv = b2[lane];
      e_a = a0 + a1 + bv;
      e_b = c0 + c1 + bv;
    }
    e_sh[la][lane] = e_a;
    e_sh[lb][lane] = e_b;
    {
      float* eo = p ? nb_e : self_e;
      eo[(size_t)(node0 + la) * 64 + lane] = e_a;
      eo[(size_t)(node0 + lb) * 64 + lane] = e_b;
    }
    __syncthreads();

    // ---- projection: s = e @ cw (+ comb_b1 for self path) ----
    a0 = a1 = c0 = c1 = 0.f;
    #pragma unroll 4
    for (int q = 0; q < 16; ++q) {
      float4 ea = *(const float4*)&e_sh[la][q * 4];
      float4 eb = *(const float4*)&e_sh[lb][q * 4];
      float w_0 = cw[(q * 4 + 0) * 64 + lane];
      float w_1 = cw[(q * 4 + 1) * 64 + lane];
      float w_2 = cw[(q * 4 + 2) * 64 + lane];
      float w_3 = cw[(q * 4 + 3) * 64 + lane];
      a0 += ea.x * w_0; a1 += ea.y * w_1; a0 += ea.z * w_2; a1 += ea.w * w_3;
      c0 += eb.x * w_0; c1 += eb.y * w_1; c0 += eb.z * w_2; c1 += eb.w * w_3;
    }
    float s_a = a0 + a1 + (p ? 0.f : cb1);
    float s_b = c0 + c1 + (p ? 0.f : cb1);
    {
      float* so = p ? sn : ss;
      so[(size_t)(node0 + la) * 64 + lane] = s_a;
      so[(size_t)(node0 + lb) * 64 + lane] = s_b;
    }
    // rank-1 terms: reduce w2*s across lanes
    float ra = w2lane * s_a, rb = w2lane * s_b;
    #pragma unroll
    for (int off = 32; off; off >>= 1) {
      ra += __shfl_xor(ra, off);
      rb += __shfl_xor(rb, off);
    }
    if (lane == 0) {
      float* po = p ? sQ : sP;
      float add = p ? 0.f : cb2;
      po[node0 + la] = 0.6f * ra + add;
      po[node0 + lb] = 0.6f * rb + add;
    }
    __syncthreads();
  }
}

// ---------------------------------------------------------------------------
// Kernel B: 512 blocks (b = blk&7 for XCD/L2 locality), 8 rows i per block,
// each wave owns 2 rows end-to-end (scores -> softmax -> aggregation).
// score(i,j) = sP_i + sQ_j + sum_k w2p_k * |ss_ik + sn_jk|   (w2p = 0.4*w2)
// ---------------------------------------------------------------------------
__global__ __launch_bounds__(256) void gat_attn(
    const int* __restrict__ edges,
    const float* __restrict__ comb_w2,
    const float* __restrict__ self_e, const float* __restrict__ nb_e,
    const float* __restrict__ ss, const float* __restrict__ sn,
    const float* __restrict__ sP, const float* __restrict__ sQ,
    float* __restrict__ out)
{
  __shared__ float ss_sh[8][64];
  __shared__ float w2s[64];
  __shared__ float sP_sh[8];
  __shared__ float sn_sh[64][68];   // padded: minimal 8-phase b128 reads
  __shared__ float sc_sh[8][512];

  const int tid = threadIdx.x, lane = tid & 63, wv = tid >> 6;
  const int blk = blockIdx.x;
  const int b = blk & 7, it = blk >> 3;
  const int i0 = it * 8;
  const size_t nodeb = (size_t)b * 512;

  if (tid < 128)
    ((float4*)&ss_sh[0][0])[tid] = ((const float4*)(ss + (nodeb + i0) * 64))[tid];
  else if (tid < 192)
    w2s[tid - 128] = 0.4f * comb_w2[tid - 128];
  else if (tid < 200)
    sP_sh[tid - 192] = sP[nodeb + i0 + (tid - 192)];
  __syncthreads();

  const int ia = wv * 2, ib = ia + 1;   // local rows owned by this wave
  const int iga = i0 + ia, igb = i0 + ib;

  // ---------------- phase 1: scores ----------------
  for (int jt = 0; jt < 8; ++jt) {
    {
      const float4* src = (const float4*)(sn + (nodeb + jt * 64) * 64);
      #pragma unroll
      for (int q = 0; q < 4; ++q) {
        int idx = q * 256 + tid;        // 0..1023 float4s
        int r = idx >> 4, c = (idx & 15) * 4;
        *(float4*)&sn_sh[r][c] = src[idx];
      }
    }
    __syncthreads();

    const int j = jt * 64 + lane;
    const int ea = edges[((size_t)b * 512 + j) * 512 + iga];
    const int eb = edges[((size_t)b * 512 + j) * 512 + igb];
    const float qj = sQ[nodeb + j];

    float acc0 = 0.f, acc1 = 0.f;
    #pragma unroll
    for (int q = 0; q < 16; ++q) {
      float4 v  = *(const float4*)&sn_sh[lane][q * 4];
      float4 w  = *(const float4*)&w2s[q * 4];
      float4 sa = *(const float4*)&ss_sh[ia][q * 4];
      float4 sb = *(const float4*)&ss_sh[ib][q * 4];
      acc0 += w.x * fabsf(sa.x + v.x);
      acc0 += w.y * fabsf(sa.y + v.y);
      acc0 += w.z * fabsf(sa.z + v.z);
      acc0 += w.w * fabsf(sa.w + v.w);
      acc1 += w.x * fabsf(sb.x + v.x);
      acc1 += w.y * fabsf(sb.y + v.y);
      acc1 += w.z * fabsf(sb.z + v.z);
      acc1 += w.w * fabsf(sb.w + v.w);
    }
    const float s0 = acc0 + sP_sh[ia] + qj;
    const float s1 = acc1 + sP_sh[ib] + qj;
    sc_sh[ia][j] = (ea != 0 && j != iga) ? s0 : -FLT_MAX;
    sc_sh[ib][j] = (eb != 0 && j != igb) ? s1 : -FLT_MAX;
    __syncthreads();
  }

  // ---------------- phase 2: softmax (wave-private rows) ----------------
  float4 pa0 = *(const float4*)&sc_sh[ia][lane * 8];
  float4 pa1 = *(const float4*)&sc_sh[ia][lane * 8 + 4];
  float4 pb0 = *(const float4*)&sc_sh[ib][lane * 8];
  float4 pb1 = *(const float4*)&sc_sh[ib][lane * 8 + 4];

  float m0 = fmaxf(fmaxf(fmaxf(pa0.x, pa0.y), fmaxf(pa0.z, pa0.w)),
                   fmaxf(fmaxf(pa1.x, pa1.y), fmaxf(pa1.z, pa1.w)));
  float m1 = fmaxf(fmaxf(fmaxf(pb0.x, pb0.y), fmaxf(pb0.z, pb0.w)),
                   fmaxf(fmaxf(pb1.x, pb1.y), fmaxf(pb1.z, pb1.w)));
  #pragma unroll
  for (int off = 32; off; off >>= 1) {
    m0 = fmaxf(m0, __shfl_xor(m0, off));
    m1 = fmaxf(m1, __shfl_xor(m1, off));
  }

  pa0.x = __expf(pa0.x - m0); pa0.y = __expf(pa0.y - m0);
  pa0.z = __expf(pa0.z - m0); pa0.w = __expf(pa0.w - m0);
  pa1.x = __expf(pa1.x - m0); pa1.y = __expf(pa1.y - m0);
  pa1.z = __expf(pa1.z - m0); pa1.w = __expf(pa1.w - m0);
  pb0.x = __expf(pb0.x - m1); pb0.y = __expf(pb0.y - m1);
  pb0.z = __expf(pb0.z - m1); pb0.w = __expf(pb0.w - m1);
  pb1.x = __expf(pb1.x - m1); pb1.y = __expf(pb1.y - m1);
  pb1.z = __expf(pb1.z - m1); pb1.w = __expf(pb1.w - m1);

  float s0 = pa0.x + pa0.y + pa0.z + pa0.w + pa1.x + pa1.y + pa1.z + pa1.w;
  float s1 = pb0.x + pb0.y + pb0.z + pb0.w + pb1.x + pb1.y + pb1.z + pb1.w;
  #pragma unroll
  for (int off = 32; off; off >>= 1) {
    s0 += __shfl_xor(s0, off);
    s1 += __shfl_xor(s1, off);
  }

  *(float4*)&sc_sh[ia][lane * 8]     = pa0;
  *(float4*)&sc_sh[ia][lane * 8 + 4] = pa1;
  *(float4*)&sc_sh[ib][lane * 8]     = pb0;
  *(float4*)&sc_sh[ib][lane * 8 + 4] = pb1;

  const float f0 = (m0 > -1e37f) ? 1.0f / s0 : 0.0f;
  const float f1 = (m1 > -1e37f) ? 1.0f / s1 : 0.0f;

  // ---------------- phase 3: aggregation (branchless) ----------------
  float acc0 = 0.f, acc1 = 0.f;
  const float* nbB = nb_e + nodeb * 64;
  #pragma unroll 4
  for (int j4 = 0; j4 < 128; ++j4) {
    float4 wa = *(const float4*)&sc_sh[ia][j4 * 4];
    float4 wb = *(const float4*)&sc_sh[ib][j4 * 4];
    const int j = j4 * 4;
    float n0 = nbB[(size_t)(j + 0) * 64 + lane];
    float n1 = nbB[(size_t)(j + 1) * 64 + lane];
    float n2 = nbB[(size_t)(j + 2) * 64 + lane];
    float n3 = nbB[(size_t)(j + 3) * 64 + lane];
    acc0 += wa.x * n0 + wa.y * n1 + wa.z * n2 + wa.w * n3;
    acc1 += wb.x * n0 + wb.y * n1 + wb.z * n2 + wb.w * n3;
  }

  const size_t oa = (nodeb + iga) * 64 + lane;
  const size_t ob = (nodeb + igb) * 64 + lane;
  out[oa] = (f0 > 0.f) ? acc0 * f0 + self_e[oa] : 0.0f;
  out[ob] = (f1 > 0.f) ? acc1 * f1 + self_e[ob] : 0.0f;
}

// ---------------------------------------------------------------------------
extern "C" void kernel_launch(void* const* d_in, const int* in_sizes, int n_in,
                              void* d_out, int out_size, void* d_ws, size_t ws_size,
                              hipStream_t stream) {
  const float* nodes   = (const float*)d_in[0];
  const int*   edges   = (const int*)  d_in[1];
  const float* self_w1 = (const float*)d_in[2];
  const float* self_b1 = (const float*)d_in[3];
  const float* self_w2 = (const float*)d_in[4];
  const float* self_b2 = (const float*)d_in[5];
  const float* nb_w1   = (const float*)d_in[6];
  const float* nb_b1   = (const float*)d_in[7];
  const float* nb_w2   = (const float*)d_in[8];
  const float* nb_b2   = (const float*)d_in[9];
  const float* comb_w1 = (const float*)d_in[10];
  const float* comb_b1 = (const float*)d_in[11];
  const float* comb_w2 = (const float*)d_in[12];
  const float* comb_b2 = (const float*)d_in[13];

  float* ws     = (float*)d_ws;
  float* self_e = ws;                  // 4096*64
  float* nb_e   = ws + 262144;         // 4096*64
  float* ss     = ws + 524288;         // 4096*64 (comb_b1 folded)
  float* sn     = ws + 786432;         // 4096*64
  float* sP     = ws + 1048576;        // 4096
  float* sQ     = ws + 1052672;        // 4096

  node_mlps<<<512, 256, 0, stream>>>(
      nodes, self_w1, self_b1, self_w2, self_b2,
      nb_w1, nb_b1, nb_w2, nb_b2, comb_w1, comb_b1, comb_w2, comb_b2,
      self_e, nb_e, ss, sn, sP, sQ);

  gat_attn<<<512, 256, 0, stream>>>(
      edges, comb_w2, self_e, nb_e, ss, sn, sP, sQ, (float*)d_out);
}

// Round 3
// 35.837 us; speedup vs baseline: 4.2663x; 1.3247x over previous
//
#include <hip/hip_runtime.h>
#include <float.h>

typedef __attribute__((ext_vector_type(8))) short short8;
typedef __attribute__((ext_vector_type(4))) float f32x4;

#define SLOPE 0.2f
// leaky(t) = 0.6t + 0.4|t| for slope 0.2

__device__ __forceinline__ float leaky(float x) { return fmaxf(x, SLOPE * x); }

// f32 -> bf16 round-to-nearest-even
__device__ __forceinline__ unsigned short f2bf(float f) {
  unsigned u = __float_as_uint(f);
  return (unsigned short)((u + 0x7FFFu + ((u >> 16) & 1u)) >> 16);
}

// ---------------------------------------------------------------------------
// Kernel A: per-node MLPs + projections + rank-1 score terms + bf16 nb^T.
//   ss  = self_e @ comb_w1[:64] + comb_b1
//   sn  = nb_e   @ comb_w1[64:]
//   sP  = 0.6*sum_k(w2_k*ss_k) + comb_b2 ; sQ = 0.6*sum_k(w2_k*sn_k)
//   nbT[b][h][j] = bf16(nb_e[b][j][h])   (MFMA B-operand layout)
// 512 blocks x 256 thr; 8 nodes/block; each wave owns 2 nodes.
// ---------------------------------------------------------------------------
__global__ __launch_bounds__(256) void node_mlps(
    const float* __restrict__ nodes,
    const float* __restrict__ self_w1, const float* __restrict__ self_b1,
    const float* __restrict__ self_w2, const float* __restrict__ self_b2,
    const float* __restrict__ nb_w1,   const float* __restrict__ nb_b1,
    const float* __restrict__ nb_w2,   const float* __restrict__ nb_b2,
    const float* __restrict__ comb_w1, const float* __restrict__ comb_b1,
    const float* __restrict__ comb_w2, const float* __restrict__ comb_b2,
    float* __restrict__ self_e,
    float* __restrict__ ss, float* __restrict__ sn,
    float* __restrict__ sP, float* __restrict__ sQ,
    unsigned short* __restrict__ nbT)
{
  __shared__ float x_sh[8][128];
  __shared__ float h_sh[8][64];
  __shared__ float e_sh[8][64];

  const int tid = threadIdx.x, lane = tid & 63, wv = tid >> 6;
  const int node0 = blockIdx.x * 8;
  const int bb = node0 >> 9;          // batch
  const int jloc = node0 & 511;       // batch-local node base

  ((float4*)&x_sh[0][0])[tid] = ((const float4*)(nodes + (size_t)node0 * 128))[tid];
  __syncthreads();

  const int la = wv * 2, lb = la + 1;
  const float w2lane = comb_w2[lane];
  const float cb2 = comb_b2[0];
  const float cb1 = comb_b1[lane];

  for (int p = 0; p < 2; ++p) {
    const float* w1 = p ? nb_w1 : self_w1;
    const float* b1 = p ? nb_b1 : self_b1;
    const float* w2 = p ? nb_w2 : self_w2;
    const float* b2 = p ? nb_b2 : self_b2;
    const float* cw = comb_w1 + (p ? 64 * 64 : 0);

    // ---- layer 1 ----
    float a0 = 0.f, a1 = 0.f, c0 = 0.f, c1 = 0.f;
    #pragma unroll 4
    for (int q = 0; q < 32; ++q) {
      float4 xa = *(const float4*)&x_sh[la][q * 4];
      float4 xb = *(const float4*)&x_sh[lb][q * 4];
      float w_0 = w1[(q * 4 + 0) * 64 + lane];
      float w_1 = w1[(q * 4 + 1) * 64 + lane];
      float w_2 = w1[(q * 4 + 2) * 64 + lane];
      float w_3 = w1[(q * 4 + 3) * 64 + lane];
      a0 += xa.x * w_0; a1 += xa.y * w_1; a0 += xa.z * w_2; a1 += xa.w * w_3;
      c0 += xb.x * w_0; c1 += xb.y * w_1; c0 += xb.z * w_2; c1 += xb.w * w_3;
    }
    {
      float bv = b1[lane];
      h_sh[la][lane] = leaky(a0 + a1 + bv);
      h_sh[lb][lane] = leaky(c0 + c1 + bv);
    }
    __syncthreads();

    // ---- layer 2 ----
    a0 = a1 = c0 = c1 = 0.f;
    #pragma unroll 4
    for (int q = 0; q < 16; ++q) {
      float4 ha = *(const float4*)&h_sh[la][q * 4];
      float4 hb = *(const float4*)&h_sh[lb][q * 4];
      float w_0 = w2[(q * 4 + 0) * 64 + lane];
      float w_1 = w2[(q * 4 + 1) * 64 + lane];
      float w_2 = w2[(q * 4 + 2) * 64 + lane];
      float w_3 = w2[(q * 4 + 3) * 64 + lane];
      a0 += ha.x * w_0; a1 += ha.y * w_1; a0 += ha.z * w_2; a1 += ha.w * w_3;
      c0 += hb.x * w_0; c1 += hb.y * w_1; c0 += hb.z * w_2; c1 += hb.w * w_3;
    }
    float e_a, e_b;
    {
      float bv = b2[lane];
      e_a = a0 + a1 + bv;
      e_b = c0 + c1 + bv;
    }
    e_sh[la][lane] = e_a;
    e_sh[lb][lane] = e_b;
    if (p == 0) {
      self_e[(size_t)(node0 + la) * 64 + lane] = e_a;
      self_e[(size_t)(node0 + lb) * 64 + lane] = e_b;
    }
    __syncthreads();

    // ---- projection ----
    a0 = a1 = c0 = c1 = 0.f;
    #pragma unroll 4
    for (int q = 0; q < 16; ++q) {
      float4 ea = *(const float4*)&e_sh[la][q * 4];
      float4 eb = *(const float4*)&e_sh[lb][q * 4];
      float w_0 = cw[(q * 4 + 0) * 64 + lane];
      float w_1 = cw[(q * 4 + 1) * 64 + lane];
      float w_2 = cw[(q * 4 + 2) * 64 + lane];
      float w_3 = cw[(q * 4 + 3) * 64 + lane];
      a0 += ea.x * w_0; a1 += ea.y * w_1; a0 += ea.z * w_2; a1 += ea.w * w_3;
      c0 += eb.x * w_0; c1 += eb.y * w_1; c0 += eb.z * w_2; c1 += eb.w * w_3;
    }
    float s_a = a0 + a1 + (p ? 0.f : cb1);
    float s_b = c0 + c1 + (p ? 0.f : cb1);
    {
      float* so = p ? sn : ss;
      so[(size_t)(node0 + la) * 64 + lane] = s_a;
      so[(size_t)(node0 + lb) * 64 + lane] = s_b;
    }
    float ra = w2lane * s_a, rb = w2lane * s_b;
    #pragma unroll
    for (int off = 32; off; off >>= 1) {
      ra += __shfl_xor(ra, off);
      rb += __shfl_xor(rb, off);
    }
    if (lane == 0) {
      float* po = p ? sQ : sP;
      float add = p ? 0.f : cb2;
      po[node0 + la] = 0.6f * ra + add;
      po[node0 + lb] = 0.6f * rb + add;
    }

    if (p == 1) {
      // nbT[b][h=lane][j]: pack this block's 2 nodes per wave (cols = lane)
      float v0 = e_sh[la][lane];
      float v1 = e_sh[lb][lane];
      unsigned pack = (unsigned)f2bf(v0) | ((unsigned)f2bf(v1) << 16);
      unsigned* dst = (unsigned*)(nbT + ((size_t)(bb * 64 + lane) * 512 + jloc + la));
      *dst = pack;
    }
    __syncthreads();
  }
}

// ---------------------------------------------------------------------------
// Kernel B: 256 blocks (b = blk&7), 16 rows/block, 512 thr (8 waves).
// Wave wv owns rows {2wv, 2wv+1} for scores+softmax; MFMA aggregation:
// wave = (N-tile = wv&3, K-half = wv>>2), D = W(16x512)@nbT(512x64) in bf16.
// ---------------------------------------------------------------------------
__global__ __launch_bounds__(512) void gat_attn(
    const int* __restrict__ edges,
    const float* __restrict__ comb_w2,
    const float* __restrict__ self_e,
    const float* __restrict__ ss, const float* __restrict__ sn,
    const float* __restrict__ sP, const float* __restrict__ sQ,
    const unsigned short* __restrict__ nbT,
    float* __restrict__ out)
{
  __shared__ __align__(16) float sn_sh[64][68];           // 17.4 KB
  __shared__ __align__(16) float sc_f[16][520];           // 33.3 KB
  __shared__ __align__(16) unsigned short sc_b[16][536];  // 17.2 KB
  __shared__ __align__(16) unsigned short nbT_sh[64][520];// 66.6 KB
  __shared__ __align__(16) float red_sh[4][64][4];        // 4 KB
  __shared__ float f_sh[16];

  const int tid = threadIdx.x, lane = tid & 63, wv = tid >> 6;
  const int blk = blockIdx.x;
  const int b = blk & 7, it = blk >> 3;
  const int i0 = it * 16;
  const size_t nodeb = (size_t)b * 512;

  const int ra = wv * 2, rb = ra + 1;     // local rows
  const int ia = i0 + ra, ib = ia + 1;    // batch-local rows

  // ---- hoist: w2p (0.4*w2), ss rows, sP scalars -> registers ----
  float4 w2p[16], sa0[16], sa1[16];
  {
    const float4* w2v = (const float4*)comb_w2;
    const float4* s0 = (const float4*)(ss + (nodeb + ia) * 64);
    const float4* s1 = (const float4*)(ss + (nodeb + ib) * 64);
    #pragma unroll
    for (int q = 0; q < 16; ++q) {
      float4 w = w2v[q];
      w2p[q] = make_float4(0.4f * w.x, 0.4f * w.y, 0.4f * w.z, 0.4f * w.w);
      sa0[q] = s0[q];
      sa1[q] = s1[q];
    }
  }
  const float sPa = sP[nodeb + ia], sPb = sP[nodeb + ib];

  // ---------------- phase 1: scores ----------------
  for (int jt = 0; jt < 8; ++jt) {
    {
      const float4* src = (const float4*)(sn + (nodeb + jt * 64) * 64);
      for (int t = tid; t < 1024; t += 512) {
        int r = t >> 4, c = (t & 15) * 4;
        *(float4*)&sn_sh[r][c] = src[t];
      }
    }
    __syncthreads();

    const int j = jt * 64 + lane;
    const int2 ee = *(const int2*)&edges[((size_t)b * 512 + j) * 512 + ia];
    const float qj = sQ[nodeb + j];

    float acc0 = 0.f, acc1 = 0.f;
    #pragma unroll
    for (int q = 0; q < 16; ++q) {
      float4 v = *(const float4*)&sn_sh[lane][q * 4];
      float4 w = w2p[q];
      float4 A = sa0[q];
      float4 Bv = sa1[q];
      acc0 += w.x * fabsf(A.x + v.x) + w.y * fabsf(A.y + v.y)
            + w.z * fabsf(A.z + v.z) + w.w * fabsf(A.w + v.w);
      acc1 += w.x * fabsf(Bv.x + v.x) + w.y * fabsf(Bv.y + v.y)
            + w.z * fabsf(Bv.z + v.z) + w.w * fabsf(Bv.w + v.w);
    }
    sc_f[ra][j] = (ee.x != 0 && j != ia) ? acc0 + sPa + qj : -FLT_MAX;
    sc_f[rb][j] = (ee.y != 0 && j != ib) ? acc1 + sPb + qj : -FLT_MAX;
    __syncthreads();
  }

  // ---------------- phase 2: softmax (wave-private rows) ----------------
  float4 pa0 = *(const float4*)&sc_f[ra][lane * 8];
  float4 pa1 = *(const float4*)&sc_f[ra][lane * 8 + 4];
  float4 pb0 = *(const float4*)&sc_f[rb][lane * 8];
  float4 pb1 = *(const float4*)&sc_f[rb][lane * 8 + 4];

  float m0 = fmaxf(fmaxf(fmaxf(pa0.x, pa0.y), fmaxf(pa0.z, pa0.w)),
                   fmaxf(fmaxf(pa1.x, pa1.y), fmaxf(pa1.z, pa1.w)));
  float m1 = fmaxf(fmaxf(fmaxf(pb0.x, pb0.y), fmaxf(pb0.z, pb0.w)),
                   fmaxf(fmaxf(pb1.x, pb1.y), fmaxf(pb1.z, pb1.w)));
  #pragma unroll
  for (int off = 32; off; off >>= 1) {
    m0 = fmaxf(m0, __shfl_xor(m0, off));
    m1 = fmaxf(m1, __shfl_xor(m1, off));
  }

  pa0.x = __expf(pa0.x - m0); pa0.y = __expf(pa0.y - m0);
  pa0.z = __expf(pa0.z - m0); pa0.w = __expf(pa0.w - m0);
  pa1.x = __expf(pa1.x - m0); pa1.y = __expf(pa1.y - m0);
  pa1.z = __expf(pa1.z - m0); pa1.w = __expf(pa1.w - m0);
  pb0.x = __expf(pb0.x - m1); pb0.y = __expf(pb0.y - m1);
  pb0.z = __expf(pb0.z - m1); pb0.w = __expf(pb0.w - m1);
  pb1.x = __expf(pb1.x - m1); pb1.y = __expf(pb1.y - m1);
  pb1.z = __expf(pb1.z - m1); pb1.w = __expf(pb1.w - m1);

  float s0 = pa0.x + pa0.y + pa0.z + pa0.w + pa1.x + pa1.y + pa1.z + pa1.w;
  float s1 = pb0.x + pb0.y + pb0.z + pb0.w + pb1.x + pb1.y + pb1.z + pb1.w;
  #pragma unroll
  for (int off = 32; off; off >>= 1) {
    s0 += __shfl_xor(s0, off);
    s1 += __shfl_xor(s1, off);
  }

  // pack exp'd (unnormalized) weights to bf16 rows
  {
    uint4 wa, wb;
    wa.x = (unsigned)f2bf(pa0.x) | ((unsigned)f2bf(pa0.y) << 16);
    wa.y = (unsigned)f2bf(pa0.z) | ((unsigned)f2bf(pa0.w) << 16);
    wa.z = (unsigned)f2bf(pa1.x) | ((unsigned)f2bf(pa1.y) << 16);
    wa.w = (unsigned)f2bf(pa1.z) | ((unsigned)f2bf(pa1.w) << 16);
    wb.x = (unsigned)f2bf(pb0.x) | ((unsigned)f2bf(pb0.y) << 16);
    wb.y = (unsigned)f2bf(pb0.z) | ((unsigned)f2bf(pb0.w) << 16);
    wb.z = (unsigned)f2bf(pb1.x) | ((unsigned)f2bf(pb1.y) << 16);
    wb.w = (unsigned)f2bf(pb1.z) | ((unsigned)f2bf(pb1.w) << 16);
    *(uint4*)&sc_b[ra][lane * 8] = wa;
    *(uint4*)&sc_b[rb][lane * 8] = wb;
  }
  if (lane == 0) {
    f_sh[ra] = (m0 > -1e37f) ? 1.0f / s0 : 0.0f;
    f_sh[rb] = (m1 > -1e37f) ? 1.0f / s1 : 0.0f;
  }
  __syncthreads();

  // ---------------- phase 3: MFMA aggregation ----------------
  {
    const short8* src = (const short8*)(nbT + (size_t)b * 64 * 512);
    for (int t = tid; t < 4096; t += 512) {
      int r = t >> 6, c = (t & 63) * 8;
      *(short8*)&nbT_sh[r][c] = src[t];
    }
  }
  __syncthreads();

  const int nt = wv & 3, kh = wv >> 2;
  const int arow = lane & 15, agrp = lane >> 4;
  const int bcol = nt * 16 + (lane & 15);

  f32x4 C = {0.f, 0.f, 0.f, 0.f};
  #pragma unroll
  for (int ks = 0; ks < 8; ++ks) {
    const int jb = kh * 256 + ks * 32 + agrp * 8;
    short8 afr = *(const short8*)&sc_b[arow][jb];
    short8 bfr = *(const short8*)&nbT_sh[bcol][jb];
    C = __builtin_amdgcn_mfma_f32_16x16x32_bf16(afr, bfr, C, 0, 0, 0);
  }
  if (kh == 1) *(f32x4*)&red_sh[wv - 4][lane][0] = C;
  __syncthreads();
  if (kh == 0) {
    f32x4 P = *(const f32x4*)&red_sh[wv][lane][0];
    #pragma unroll
    for (int r = 0; r < 4; ++r) {
      const int rg = agrp * 4 + r;           // C/D: row=(lane>>4)*4+reg
      const float f = f_sh[rg];
      const size_t adr = (nodeb + i0 + rg) * 64 + bcol;
      const float val = (C[r] + P[r]) * f + self_e[adr];
      out[adr] = (f > 0.f) ? val : 0.f;
    }
  }
}

// ---------------------------------------------------------------------------
extern "C" void kernel_launch(void* const* d_in, const int* in_sizes, int n_in,
                              void* d_out, int out_size, void* d_ws, size_t ws_size,
                              hipStream_t stream) {
  const float* nodes   = (const float*)d_in[0];
  const int*   edges   = (const int*)  d_in[1];
  const float* self_w1 = (const float*)d_in[2];
  const float* self_b1 = (const float*)d_in[3];
  const float* self_w2 = (const float*)d_in[4];
  const float* self_b2 = (const float*)d_in[5];
  const float* nb_w1   = (const float*)d_in[6];
  const float* nb_b1   = (const float*)d_in[7];
  const float* nb_w2   = (const float*)d_in[8];
  const float* nb_b2   = (const float*)d_in[9];
  const float* comb_w1 = (const float*)d_in[10];
  const float* comb_b1 = (const float*)d_in[11];
  const float* comb_w2 = (const float*)d_in[12];
  const float* comb_b2 = (const float*)d_in[13];

  float* ws     = (float*)d_ws;
  float* self_e = ws;                       // 262144
  float* ss     = ws + 262144;              // 262144
  float* sn     = ws + 524288;              // 262144
  float* sP     = ws + 786432;              // 4096
  float* sQ     = ws + 790528;              // 4096
  unsigned short* nbT = (unsigned short*)(ws + 794624);  // 262144 bf16

  node_mlps<<<512, 256, 0, stream>>>(
      nodes, self_w1, self_b1, self_w2, self_b2,
      nb_w1, nb_b1, nb_w2, nb_b2, comb_w1, comb_b1, comb_w2, comb_b2,
      self_e, ss, sn, sP, sQ, nbT);

  gat_attn<<<256, 512, 0, stream>>>(
      edges, comb_w2, self_e, ss, sn, sP, sQ, nbT, (float*)d_out);
}